// Round 4
// baseline (29493.597 us; speedup 1.0000x reference)
//
#include <hip/hip_runtime.h>

// ---------------------------------------------------------------------------
// LayerNorm-LSTM (2 layers) + softmax head.  B=1024 T=100 D=300 U=512 C=14
// Round 4: single persistent kernel for the whole recurrence.
//   Batch rows are independent through time -> block owns 16 rows, loops
//   t=0..99 internally. 64 blocks x 1024 thr (16 waves). Wave = 128 z-cols.
//   z exchange wave<->wave via per-block private global scratch (no LDS).
//   h0/h1 f16 in per-block global scratch; c in registers. Head fused.
//   6 dispatches total (was ~410) -- kills dispatch overhead.
// ---------------------------------------------------------------------------

typedef _Float16 f16;
typedef _Float16 f16x8 __attribute__((ext_vector_type(8)));
typedef float f32x4 __attribute__((ext_vector_type(4)));

// ---------------------------------------------------------------------------
// W [K,N] fp32 row-major -> Bt [N,Kp] f16 row-major, zero-padded k in [K,Kp)
// ---------------------------------------------------------------------------
__global__ __launch_bounds__(256) void transpose_f16(
    const float* __restrict__ W, f16* __restrict__ Bt, int K, int N, int Kp) {
  __shared__ float s[32][33];
  int n0 = blockIdx.x * 32, k0 = blockIdx.y * 32;
  int tid = threadIdx.x, c = tid & 31, r8 = tid >> 5;
  for (int rr = r8; rr < 32; rr += 8) {
    int k = k0 + rr;
    s[rr][c] = (k < K) ? W[(long)k * N + (n0 + c)] : 0.0f;
  }
  __syncthreads();
  for (int rr = r8; rr < 32; rr += 8)
    Bt[(long)(n0 + rr) * Kp + (k0 + c)] = (f16)s[c][rr];
}

// bb = beta + bias for both layers (2048 each)
__global__ __launch_bounds__(256) void fold_bias(
    const float* __restrict__ be0, const float* __restrict__ b0,
    const float* __restrict__ be1, const float* __restrict__ b1,
    float* __restrict__ bb0, float* __restrict__ bb1) {
  int i = blockIdx.x * 256 + threadIdx.x;
  if (i < 2048) bb0[i] = be0[i] + b0[i];
  else if (i < 4096) bb1[i - 2048] = be1[i - 2048] + b1[i - 2048];
}

// ---------------------------------------------------------------------------
// GEMM sub-phase: acc += A[16,512] @ Bt^T  (A = h state, f16, global)
// wave covers cols [colb, colb+128), frag j col = colb + j*16 + l15
// ---------------------------------------------------------------------------
__device__ __forceinline__ void gemm_acc(
    f32x4 acc[8], const f16* __restrict__ A, const f16* __restrict__ Bt,
    int colb, int l15, int quad) {
  const f16* ar = A + l15 * 512 + quad * 8;
  const f16* bb[8];
#pragma unroll
  for (int j = 0; j < 8; ++j)
    bb[j] = Bt + (long)(colb + j * 16 + l15) * 512 + quad * 8;
  for (int k0 = 0; k0 < 512; k0 += 32) {
    f16x8 afr = *(const f16x8*)(ar + k0);
    f16x8 bfr[8];
#pragma unroll
    for (int j = 0; j < 8; ++j) bfr[j] = *(const f16x8*)(bb[j] + k0);
#pragma unroll
    for (int j = 0; j < 8; ++j)
      acc[j] = __builtin_amdgcn_mfma_f32_16x16x32_f16(afr, bfr[j], acc[j], 0, 0, 0);
  }
}

// ---------------------------------------------------------------------------
// LN + gates + c/h update for one row (wave = row). zv per gate over 512.
// ---------------------------------------------------------------------------
__device__ __forceinline__ void gates_phase(
    const float* __restrict__ zs, const float* __restrict__ gamma,
    const float* __restrict__ bb, bool m, float* cr, f16* __restrict__ h,
    int row, int lane) {
  float zv[4][8], sum[4], sq[4];
#pragma unroll
  for (int g = 0; g < 4; ++g) {
    sum[g] = 0.f; sq[g] = 0.f;
#pragma unroll
    for (int i = 0; i < 8; ++i) {
      float v = zs[row * 2048 + g * 512 + lane + 64 * i];
      zv[g][i] = v; sum[g] += v; sq[g] += v * v;
    }
  }
#pragma unroll
  for (int off = 32; off >= 1; off >>= 1) {
#pragma unroll
    for (int g = 0; g < 4; ++g) {
      sum[g] += __shfl_xor(sum[g], off);
      sq[g] += __shfl_xor(sq[g], off);
    }
  }
  float act[4][8];
#pragma unroll
  for (int g = 0; g < 4; ++g) {
    float mu = sum[g] * (1.f / 512.f);
    float var = sq[g] * (1.f / 512.f) - mu * mu;
    float is = rsqrtf(var + 1e-3f);
#pragma unroll
    for (int i = 0; i < 8; ++i) {
      int u = g * 512 + lane + 64 * i;
      float val = gamma[u] * (zv[g][i] - mu) * is + bb[u];
      act[g][i] = (g == 2) ? (2.f / (1.f + __expf(-2.f * val)) - 1.f)   // tanh
                           : (1.f / (1.f + __expf(-val)));              // sigmoid
    }
  }
  if (m) {   // wave-uniform; masked steps carry h,c through
#pragma unroll
    for (int i = 0; i < 8; ++i) {
      float cn = act[1][i] * cr[i] + act[0][i] * act[2][i];
      cr[i] = cn;
      float th = 2.f / (1.f + __expf(-2.f * cn)) - 1.f;
      h[row * 512 + lane + 64 * i] = (f16)(act[3][i] * th);
    }
  }
}

// ---------------------------------------------------------------------------
__global__ __launch_bounds__(1024) void lstm_all(
    const float* __restrict__ x, const int* __restrict__ mask,
    const f16* __restrict__ W0t, const f16* __restrict__ U0t,
    const f16* __restrict__ W1t, const f16* __restrict__ U1t,
    const float* __restrict__ g0, const float* __restrict__ bb0,
    const float* __restrict__ g1, const float* __restrict__ bb1,
    const float* __restrict__ Wd, const float* __restrict__ bd,
    f16* __restrict__ h0g, f16* __restrict__ h1g, float* __restrict__ zg,
    float* __restrict__ out) {
  const int tid = threadIdx.x;
  const int w = tid >> 6, lane = tid & 63;
  const int l15 = lane & 15, quad = lane >> 4;
  const int R0 = blockIdx.x * 16;
  const int colb = w * 128;

  f16* h0 = h0g + (long)blockIdx.x * 8192;       // [16][512] f16, block-private
  f16* h1 = h1g + (long)blockIdx.x * 8192;
  float* zs = zg + (long)blockIdx.x * 32768;     // [16][2048] f32, block-private

  for (int i = tid; i < 8192; i += 1024) { h0[i] = (f16)0.f; h1[i] = (f16)0.f; }
  float c0r[8], c1r[8];
#pragma unroll
  for (int i = 0; i < 8; ++i) { c0r[i] = 0.f; c1r[i] = 0.f; }
  __syncthreads();

  for (int t = 0; t < 100; ++t) {
    bool m = mask[(long)(R0 + w) * 100 + t] > 0;

    // ===== layer 0: z = x_t @ W0 + h0 @ U0 =====
    f32x4 acc[8];
#pragma unroll
    for (int j = 0; j < 8; ++j) acc[j] = (f32x4){0.f, 0.f, 0.f, 0.f};
    {
      const float* xrow = x + ((long)(R0 + l15) * 100 + t) * 300;
      const f16* bb[8];
#pragma unroll
      for (int j = 0; j < 8; ++j)
        bb[j] = W0t + (long)(colb + j * 16 + l15) * 320 + quad * 8;
      for (int k0 = 0; k0 < 288; k0 += 32) {   // full chunks (16B-aligned: 300*4 row stride is 16-mult)
        const float* xp = xrow + k0 + quad * 8;
        float4 p0 = *(const float4*)xp;
        float4 p1 = *(const float4*)(xp + 4);
        f16x8 afr = {(f16)p0.x, (f16)p0.y, (f16)p0.z, (f16)p0.w,
                     (f16)p1.x, (f16)p1.y, (f16)p1.z, (f16)p1.w};
        f16x8 bfr[8];
#pragma unroll
        for (int j = 0; j < 8; ++j) bfr[j] = *(const f16x8*)(bb[j] + k0);
#pragma unroll
        for (int j = 0; j < 8; ++j)
          acc[j] = __builtin_amdgcn_mfma_f32_16x16x32_f16(afr, bfr[j], acc[j], 0, 0, 0);
      }
      {  // k0=288 chunk: k in [288,320), valid < 300 -> guarded loads
        f16x8 afr;
#pragma unroll
        for (int e = 0; e < 8; ++e) {
          int k = 288 + quad * 8 + e;
          float v = 0.f;
          if (k < 300) v = xrow[k];
          afr[e] = (f16)v;
        }
        f16x8 bfr[8];
#pragma unroll
        for (int j = 0; j < 8; ++j) bfr[j] = *(const f16x8*)(bb[j] + 288);
#pragma unroll
        for (int j = 0; j < 8; ++j)
          acc[j] = __builtin_amdgcn_mfma_f32_16x16x32_f16(afr, bfr[j], acc[j], 0, 0, 0);
      }
    }
    gemm_acc(acc, h0, U0t, colb, l15, quad);
#pragma unroll
    for (int j = 0; j < 8; ++j)
#pragma unroll
      for (int r = 0; r < 4; ++r)
        zs[(quad * 4 + r) * 2048 + colb + j * 16 + l15] = acc[j][r];
    __syncthreads();
    gates_phase(zs, g0, bb0, m, c0r, h0, w, lane);
    __syncthreads();

    // ===== layer 1: z = h0 @ W1 + h1 @ U1 =====
#pragma unroll
    for (int j = 0; j < 8; ++j) acc[j] = (f32x4){0.f, 0.f, 0.f, 0.f};
    gemm_acc(acc, h0, W1t, colb, l15, quad);
    gemm_acc(acc, h1, U1t, colb, l15, quad);
#pragma unroll
    for (int j = 0; j < 8; ++j)
#pragma unroll
      for (int r = 0; r < 4; ++r)
        zs[(quad * 4 + r) * 2048 + colb + j * 16 + l15] = acc[j][r];
    __syncthreads();
    gates_phase(zs, g1, bb1, m, c1r, h1, w, lane);
    __syncthreads();
  }

  // ===== head: out[row] = softmax(h1[row] @ Wd + bd) =====
  {
    const int row = w;
    float s = (lane < 14) ? bd[lane] : -1e30f;
    for (int k = 0; k < 512; ++k) {
      float hv = (float)h1[row * 512 + k];
      if (lane < 14) s += hv * Wd[k * 14 + lane];
    }
    float mx = s;
#pragma unroll
    for (int off = 8; off >= 1; off >>= 1) mx = fmaxf(mx, __shfl_xor(mx, off, 16));
    float e = __expf(s - mx);
    float den = e;
#pragma unroll
    for (int off = 8; off >= 1; off >>= 1) den += __shfl_xor(den, off, 16);
    if (lane < 14) out[(long)(R0 + row) * 14 + lane] = e / den;
  }
}

// ---------------------------------------------------------------------------
extern "C" void kernel_launch(void* const* d_in, const int* in_sizes, int n_in,
                              void* d_out, int out_size, void* d_ws, size_t ws_size,
                              hipStream_t stream) {
  const float* x   = (const float*)d_in[0];
  const int* mask  = (const int*)d_in[1];
  const float* W0  = (const float*)d_in[2];
  const float* U0w = (const float*)d_in[3];
  const float* b0  = (const float*)d_in[4];
  const float* g0  = (const float*)d_in[5];
  const float* be0 = (const float*)d_in[6];
  const float* W1  = (const float*)d_in[7];
  const float* U1w = (const float*)d_in[8];
  const float* b1  = (const float*)d_in[9];
  const float* g1  = (const float*)d_in[10];
  const float* be1 = (const float*)d_in[11];
  const float* Wd  = (const float*)d_in[12];
  const float* bd  = (const float*)d_in[13];
  float* out = (float*)d_out;

  char* p = (char*)d_ws;
  f16*   W0t = (f16*)(p);                               // 2048*320*2 = 1,310,720
  f16*   U0t = (f16*)(p + 1310720);                     // 2048*512*2 = 2,097,152
  f16*   W1t = (f16*)(p + 3407872);
  f16*   U1t = (f16*)(p + 5505024);
  float* bb0 = (float*)(p + 7602176);                   // 8 KB
  float* bb1 = (float*)(p + 7610368);                   // 8 KB
  f16*   h0g = (f16*)(p + 7618560);                     // 64*8192*2 = 1 MB
  f16*   h1g = (f16*)(p + 8667136);                     // 1 MB
  float* zg  = (float*)(p + 9715712);                   // 64*32768*4 = 8 MB
  // total ~17.7 MB (R2 passed with unguarded 24.7 MB use -> ws is big enough)

  transpose_f16<<<dim3(64, 10), 256, 0, stream>>>(W0,  W0t, 300, 2048, 320);
  transpose_f16<<<dim3(64, 16), 256, 0, stream>>>(U0w, U0t, 512, 2048, 512);
  transpose_f16<<<dim3(64, 16), 256, 0, stream>>>(W1,  W1t, 512, 2048, 512);
  transpose_f16<<<dim3(64, 16), 256, 0, stream>>>(U1w, U1t, 512, 2048, 512);
  fold_bias<<<16, 256, 0, stream>>>(be0, b0, be1, b1, bb0, bb1);

  lstm_all<<<64, 1024, 0, stream>>>(x, mask, W0t, U0t, W1t, U1t,
                                    g0, bb0, g1, bb1, Wd, bd,
                                    h0g, h1g, zg, out);
}

// Round 7
// 10936.058 us; speedup vs baseline: 2.6969x; 2.6969x over previous
//
#include <hip/hip_runtime.h>

// ---------------------------------------------------------------------------
// LayerNorm-LSTM (2 layers) + softmax head.  B=1024 T=100 D=300 U=512 C=14
// Round 7: R6 with the layer-0 K-tail indexing fix (quad*8 was double-counted
//   -> quad=1 lanes read x[304..307] instead of x[296..299]).
//   Persistent kernel, regular launch, manual 2-level grid barrier.
//   Layer-pipelined: iteration i computes z0(t=i) AND z1(t=i-1) in one GEMM
//   phase (h0 A-frags shared by U0/W1 terms). Gates spread 4 rows x 2 layers
//   per block. 2 device-scope barriers per iteration, 101 iterations.
// ---------------------------------------------------------------------------

typedef _Float16 f16;
typedef _Float16 f16x8 __attribute__((ext_vector_type(8)));
typedef float f32x4 __attribute__((ext_vector_type(4)));

// ---------------------------------------------------------------------------
__global__ __launch_bounds__(256) void transpose_f16(
    const float* __restrict__ W, f16* __restrict__ Bt, int K, int N, int Kp) {
  __shared__ float s[32][33];
  int n0 = blockIdx.x * 32, k0 = blockIdx.y * 32;
  int tid = threadIdx.x, c = tid & 31, r8 = tid >> 5;
  for (int rr = r8; rr < 32; rr += 8) {
    int k = k0 + rr;
    s[rr][c] = (k < K) ? W[(long)k * N + (n0 + c)] : 0.0f;
  }
  __syncthreads();
  for (int rr = r8; rr < 32; rr += 8)
    Bt[(long)(n0 + rr) * Kp + (k0 + c)] = (f16)s[c][rr];
}

__global__ __launch_bounds__(256) void fold_bias(
    const float* __restrict__ be0, const float* __restrict__ b0,
    const float* __restrict__ be1, const float* __restrict__ b1,
    float* __restrict__ bb0, float* __restrict__ bb1) {
  int i = blockIdx.x * 256 + threadIdx.x;
  if (i < 2048) bb0[i] = be0[i] + b0[i];
  else if (i < 4096) bb1[i - 2048] = be1[i - 2048] + b1[i - 2048];
}

// ---------------------------------------------------------------------------
__device__ __forceinline__ float sigm(float v) { return 1.f / (1.f + __expf(-v)); }
__device__ __forceinline__ float tanh_(float v) { return 2.f / (1.f + __expf(-2.f * v)) - 1.f; }

// two-level grid barrier: monotonic counters, agent-scope atomics.
// bar[0]=gen, bar[32]=root, bar[64 + g*32]=group counters (g = bx&7).
__device__ __forceinline__ void gbar(unsigned* bar, int g8) {
  __syncthreads();
  if (threadIdx.x == 0) {
    unsigned g = __hip_atomic_load(bar, __ATOMIC_RELAXED, __HIP_MEMORY_SCOPE_AGENT);
    unsigned a = __hip_atomic_fetch_add(bar + 64 + g8 * 32, 1u, __ATOMIC_ACQ_REL,
                                        __HIP_MEMORY_SCOPE_AGENT);
    if ((a & 31u) == 31u) {  // last of the 32 blocks in this group
      unsigned r = __hip_atomic_fetch_add(bar + 32, 1u, __ATOMIC_ACQ_REL,
                                          __HIP_MEMORY_SCOPE_AGENT);
      if ((r & 7u) == 7u)    // last group
        __hip_atomic_store(bar, g + 1u, __ATOMIC_RELEASE, __HIP_MEMORY_SCOPE_AGENT);
    }
    while (__hip_atomic_load(bar, __ATOMIC_ACQUIRE, __HIP_MEMORY_SCOPE_AGENT) == g)
      __builtin_amdgcn_s_sleep(4);
  }
  __syncthreads();
}

// ---------------------------------------------------------------------------
// LN + gates + c/h in-place update for one (row, layer).  32 threads/row,
// thread j handles cols [j*16, j*16+16) of each gate.
// ---------------------------------------------------------------------------
__device__ __forceinline__ void gates_row(
    const float* __restrict__ z, const float* __restrict__ gamma,
    const float* __restrict__ bb, float* __restrict__ c, f16* __restrict__ h,
    const int* __restrict__ mask, int row, int t, int j) {
  const float* zr = z + (long)row * 2048;
  float zv[4][16], mu[4], is[4];
#pragma unroll
  for (int g = 0; g < 4; ++g) {
    const float4* zp = (const float4*)(zr + g * 512 + j * 16);
    float sum = 0.f, sq = 0.f;
#pragma unroll
    for (int e = 0; e < 4; ++e) {
      float4 v = zp[e];
      zv[g][e * 4 + 0] = v.x; zv[g][e * 4 + 1] = v.y;
      zv[g][e * 4 + 2] = v.z; zv[g][e * 4 + 3] = v.w;
      sum += v.x + v.y + v.z + v.w;
      sq += v.x * v.x + v.y * v.y + v.z * v.z + v.w * v.w;
    }
#pragma unroll
    for (int off = 1; off <= 16; off <<= 1) {
      sum += __shfl_xor(sum, off);
      sq += __shfl_xor(sq, off);
    }
    mu[g] = sum * (1.f / 512.f);
    is[g] = rsqrtf(sq * (1.f / 512.f) - mu[g] * mu[g] + 1e-3f);
  }
  bool m = mask[(long)row * 100 + t] > 0;
  float cb[16], hb[16];
  {
    const float4* cp = (const float4*)(c + (long)row * 512 + j * 16);
#pragma unroll
    for (int e4 = 0; e4 < 4; ++e4) *(float4*)&cb[e4 * 4] = cp[e4];
    f16x8 h0v = *(const f16x8*)(h + (long)row * 512 + j * 16);
    f16x8 h1v = *(const f16x8*)(h + (long)row * 512 + j * 16 + 8);
#pragma unroll
    for (int e = 0; e < 8; ++e) { hb[e] = (float)h0v[e]; hb[8 + e] = (float)h1v[e]; }
  }
#pragma unroll
  for (int e = 0; e < 16; ++e) {
    int u = j * 16 + e;
    float iv = sigm(gamma[u] * (zv[0][e] - mu[0]) * is[0] + bb[u]);
    float fv = sigm(gamma[512 + u] * (zv[1][e] - mu[1]) * is[1] + bb[512 + u]);
    float cv = tanh_(gamma[1024 + u] * (zv[2][e] - mu[2]) * is[2] + bb[1024 + u]);
    float ov = sigm(gamma[1536 + u] * (zv[3][e] - mu[3]) * is[3] + bb[1536 + u]);
    float co = cb[e], ho = hb[e];
    float cn = fv * co + iv * cv;
    float hn = ov * tanh_(cn);
    if (!m) { cn = co; hn = ho; }
    cb[e] = cn; hb[e] = hn;
  }
  {
    float4* cp = (float4*)(c + (long)row * 512 + j * 16);
#pragma unroll
    for (int e4 = 0; e4 < 4; ++e4) cp[e4] = *(const float4*)&cb[e4 * 4];
    f16x8 h0v, h1v;
#pragma unroll
    for (int e = 0; e < 8; ++e) { h0v[e] = (f16)hb[e]; h1v[e] = (f16)hb[8 + e]; }
    *(f16x8*)(h + (long)row * 512 + j * 16) = h0v;
    *(f16x8*)(h + (long)row * 512 + j * 16 + 8) = h1v;
  }
}

// ---------------------------------------------------------------------------
__global__ __launch_bounds__(256) void lstm_all(
    const float* __restrict__ x, const int* __restrict__ mask,
    const f16* __restrict__ W0t, const f16* __restrict__ U0t,
    const f16* __restrict__ W1t, const f16* __restrict__ U1t,
    const float* __restrict__ g0, const float* __restrict__ bb0,
    const float* __restrict__ g1, const float* __restrict__ bb1,
    const float* __restrict__ Wd, const float* __restrict__ bd,
    float* __restrict__ z0, float* __restrict__ z1,
    f16* __restrict__ h0, f16* __restrict__ h1,
    float* __restrict__ c0, float* __restrict__ c1,
    unsigned* __restrict__ bar, float* __restrict__ out) {
  const int tid = threadIdx.x;
  const int w = tid >> 6, lane = tid & 63;
  const int l15 = lane & 15, quad = lane >> 4;
  const int bx = blockIdx.x;
  const int g8 = bx & 7;
  const int nt = bx & 15, mt = bx >> 4;
  const int R0 = mt * 64;            // 64-row m-tile
  const int CW = nt * 128 + w * 32;  // wave's 32-col base

  for (int i = 0; i <= 100; ++i) {
    // ================= GEMM phase: z0(i) [i<100], z1(i-1) [i>=1] ============
    f32x4 acc0[4][2], acc1[4][2];
#pragma unroll
    for (int a = 0; a < 4; ++a)
#pragma unroll
      for (int b = 0; b < 2; ++b) {
        acc0[a][b] = (f32x4){0.f, 0.f, 0.f, 0.f};
        acc1[a][b] = (f32x4){0.f, 0.f, 0.f, 0.f};
      }

    if (i < 100) {  // x(i) @ W0 -> acc0
      const float* xr[4];
#pragma unroll
      for (int a = 0; a < 4; ++a)
        xr[a] = x + ((long)(R0 + a * 16 + l15) * 100 + i) * 300 + quad * 8;
      const f16* bp = W0t + (long)(CW + l15) * 320 + quad * 8;
#pragma unroll
      for (int k0 = 0; k0 < 288; k0 += 32) {
        f16x8 af[4];
#pragma unroll
        for (int a = 0; a < 4; ++a) {
          float4 p0 = *(const float4*)(xr[a] + k0);
          float4 p1 = *(const float4*)(xr[a] + k0 + 4);
          af[a] = (f16x8){(f16)p0.x, (f16)p0.y, (f16)p0.z, (f16)p0.w,
                          (f16)p1.x, (f16)p1.y, (f16)p1.z, (f16)p1.w};
        }
        f16x8 bf[2];
#pragma unroll
        for (int b = 0; b < 2; ++b) bf[b] = *(const f16x8*)(bp + (long)b * 16 * 320 + k0);
#pragma unroll
        for (int a = 0; a < 4; ++a)
#pragma unroll
          for (int b = 0; b < 2; ++b)
            acc0[a][b] = __builtin_amdgcn_mfma_f32_16x16x32_f16(af[a], bf[b], acc0[a][b], 0, 0, 0);
      }
      {  // tail chunk: global k = 288 + quad*8 + e, valid < 300.
         // xr[a] already includes +quad*8, so the element is xr[a][288 + e].
        f16x8 af[4];
#pragma unroll
        for (int a = 0; a < 4; ++a)
#pragma unroll
          for (int e = 0; e < 8; ++e) {
            int kg = 288 + quad * 8 + e;
            af[a][e] = (kg < 300) ? (f16)xr[a][288 + e] : (f16)0.f;
          }
        f16x8 bf[2];
#pragma unroll
        for (int b = 0; b < 2; ++b) bf[b] = *(const f16x8*)(bp + (long)b * 16 * 320 + 288);
#pragma unroll
        for (int a = 0; a < 4; ++a)
#pragma unroll
          for (int b = 0; b < 2; ++b)
            acc0[a][b] = __builtin_amdgcn_mfma_f32_16x16x32_f16(af[a], bf[b], acc0[a][b], 0, 0, 0);
      }
    }

    {  // h0 @ U0 -> acc0 [i<100]  and  h0 @ W1 -> acc1 [i>=1]  (shared A frags)
      const f16* ap = h0 + (long)(R0 + l15) * 512 + quad * 8;
      const f16* up = U0t + (long)(CW + l15) * 512 + quad * 8;
      const f16* wp = W1t + (long)(CW + l15) * 512 + quad * 8;
#pragma unroll 4
      for (int k0 = 0; k0 < 512; k0 += 32) {
        f16x8 af[4];
#pragma unroll
        for (int a = 0; a < 4; ++a) af[a] = *(const f16x8*)(ap + (long)a * 16 * 512 + k0);
        if (i < 100) {
          f16x8 bf[2];
#pragma unroll
          for (int b = 0; b < 2; ++b) bf[b] = *(const f16x8*)(up + (long)b * 16 * 512 + k0);
#pragma unroll
          for (int a = 0; a < 4; ++a)
#pragma unroll
            for (int b = 0; b < 2; ++b)
              acc0[a][b] = __builtin_amdgcn_mfma_f32_16x16x32_f16(af[a], bf[b], acc0[a][b], 0, 0, 0);
        }
        if (i >= 1) {
          f16x8 bf[2];
#pragma unroll
          for (int b = 0; b < 2; ++b) bf[b] = *(const f16x8*)(wp + (long)b * 16 * 512 + k0);
#pragma unroll
          for (int a = 0; a < 4; ++a)
#pragma unroll
            for (int b = 0; b < 2; ++b)
              acc1[a][b] = __builtin_amdgcn_mfma_f32_16x16x32_f16(af[a], bf[b], acc1[a][b], 0, 0, 0);
        }
      }
    }

    if (i >= 1) {  // h1 @ U1 -> acc1
      const f16* ap = h1 + (long)(R0 + l15) * 512 + quad * 8;
      const f16* up = U1t + (long)(CW + l15) * 512 + quad * 8;
#pragma unroll 4
      for (int k0 = 0; k0 < 512; k0 += 32) {
        f16x8 af[4];
#pragma unroll
        for (int a = 0; a < 4; ++a) af[a] = *(const f16x8*)(ap + (long)a * 16 * 512 + k0);
        f16x8 bf[2];
#pragma unroll
        for (int b = 0; b < 2; ++b) bf[b] = *(const f16x8*)(up + (long)b * 16 * 512 + k0);
#pragma unroll
        for (int a = 0; a < 4; ++a)
#pragma unroll
          for (int b = 0; b < 2; ++b)
            acc1[a][b] = __builtin_amdgcn_mfma_f32_16x16x32_f16(af[a], bf[b], acc1[a][b], 0, 0, 0);
      }
    }

    // write z  (D mapping: col=lane&15, row=quad*4+r)
    if (i < 100) {
#pragma unroll
      for (int a = 0; a < 4; ++a)
#pragma unroll
        for (int b = 0; b < 2; ++b)
#pragma unroll
          for (int r = 0; r < 4; ++r)
            z0[(long)(R0 + a * 16 + quad * 4 + r) * 2048 + CW + b * 16 + l15] = acc0[a][b][r];
    }
    if (i >= 1) {
#pragma unroll
      for (int a = 0; a < 4; ++a)
#pragma unroll
        for (int b = 0; b < 2; ++b)
#pragma unroll
          for (int r = 0; r < 4; ++r)
            z1[(long)(R0 + a * 16 + quad * 4 + r) * 2048 + CW + b * 16 + l15] = acc1[a][b][r];
    }
    gbar(bar, g8);

    // ================= gates phase: h0(i), h1(i-1), spread ==================
    {
      int slot = tid >> 5;           // 0..7
      int layer = slot >> 2;         // 0,1
      int row = bx * 4 + (slot & 3);
      int t = i - layer;
      int j = tid & 31;
      if (layer == 0) {
        if (t <= 99) gates_row(z0, g0, bb0, c0, h0, mask, row, t, j);
      } else {
        if (t >= 0) gates_row(z1, g1, bb1, c1, h1, mask, row, t, j);
      }
    }
    gbar(bar, g8);
  }

  // ================= head: out = softmax(h1 @ Wd + bd) ======================
  {
    int lr = tid >> 3, seg = tid & 7;
    if (lr < 4) {
      long grow = (long)bx * 4 + lr;
      const f16* hr = h1 + grow * 512 + seg * 64;
      float part[14];
#pragma unroll
      for (int c2 = 0; c2 < 14; ++c2) part[c2] = 0.f;
      for (int k = 0; k < 64; ++k) {
        float hv = (float)hr[k];
        const float* wd = Wd + (long)(seg * 64 + k) * 14;
#pragma unroll
        for (int c2 = 0; c2 < 14; ++c2) part[c2] += hv * wd[c2];
      }
#pragma unroll
      for (int c2 = 0; c2 < 14; ++c2)
#pragma unroll
        for (int off = 1; off <= 4; off <<= 1)
          part[c2] += __shfl_xor(part[c2], off);
      if (seg == 0) {
        float lg[14], mx = -1e30f;
#pragma unroll
        for (int c2 = 0; c2 < 14; ++c2) { lg[c2] = part[c2] + bd[c2]; mx = fmaxf(mx, lg[c2]); }
        float den = 0.f, ev[14];
#pragma unroll
        for (int c2 = 0; c2 < 14; ++c2) { ev[c2] = __expf(lg[c2] - mx); den += ev[c2]; }
        float rden = 1.f / den;
#pragma unroll
        for (int c2 = 0; c2 < 14; ++c2) out[grow * 14 + c2] = ev[c2] * rden;
      }
    }
  }
}

// ---------------------------------------------------------------------------
extern "C" void kernel_launch(void* const* d_in, const int* in_sizes, int n_in,
                              void* d_out, int out_size, void* d_ws, size_t ws_size,
                              hipStream_t stream) {
  const float* x   = (const float*)d_in[0];
  const int* mask  = (const int*)d_in[1];
  const float* W0  = (const float*)d_in[2];
  const float* U0w = (const float*)d_in[3];
  const float* b0  = (const float*)d_in[4];
  const float* g0  = (const float*)d_in[5];
  const float* be0 = (const float*)d_in[6];
  const float* W1  = (const float*)d_in[7];
  const float* U1w = (const float*)d_in[8];
  const float* b1  = (const float*)d_in[9];
  const float* g1  = (const float*)d_in[10];
  const float* be1 = (const float*)d_in[11];
  const float* Wd  = (const float*)d_in[12];
  const float* bd  = (const float*)d_in[13];
  float* out = (float*)d_out;

  char* p = (char*)d_ws;
  unsigned* bar = (unsigned*)(p);               // 4 KB
  f16*   h0  = (f16*)(p + 4096);                // 1 MB
  f16*   h1  = (f16*)(p + 1052672);             // 1 MB
  float* c0  = (float*)(p + 2101248);           // 2 MB
  float* c1  = (float*)(p + 4198400);           // 2 MB
  // --- zero region ends at 6295552 ---
  float* z0  = (float*)(p + 6295552);           // 8 MB
  float* z1  = (float*)(p + 14684160);          // 8 MB
  f16*   W0t = (f16*)(p + 23072768);            // 2048*320*2
  f16*   U0t = (f16*)(p + 24383488);            // 2048*512*2
  f16*   W1t = (f16*)(p + 26480640);
  f16*   U1t = (f16*)(p + 28577792);
  float* bb0 = (float*)(p + 30674944);          // 8 KB
  float* bb1 = (float*)(p + 30683136);          // ~30.7 MB total

  hipMemsetAsync(p, 0, 6295552, stream);        // bar + h0 + h1 + c0 + c1

  transpose_f16<<<dim3(64, 10), 256, 0, stream>>>(W0,  W0t, 300, 2048, 320);
  transpose_f16<<<dim3(64, 16), 256, 0, stream>>>(U0w, U0t, 512, 2048, 512);
  transpose_f16<<<dim3(64, 16), 256, 0, stream>>>(W1,  W1t, 512, 2048, 512);
  transpose_f16<<<dim3(64, 16), 256, 0, stream>>>(U1w, U1t, 512, 2048, 512);
  fold_bias<<<16, 256, 0, stream>>>(be0, b0, be1, b1, bb0, bb1);

  lstm_all<<<256, 256, 0, stream>>>(x, mask, W0t, U0t, W1t, U1t,
                                    g0, bb0, g1, bb1, Wd, bd,
                                    z0, z1, h0, h1, c0, c1, bar, out);
}